// Round 3
// baseline (348.690 us; speedup 1.0000x reference)
//
#include <hip/hip_runtime.h>
#include <math.h>
#include <stdint.h>

// Problem constants
#define TM 16384   // B*C*T rows
#define NN 512     // DOUT
#define KDIM 1536  // DIN
#define BM 128
#define BN 128
#define BKS 32
#define NKT 48     // total K-steps (full K per block: tanh needs complete z)

typedef _Float16 f16x8 __attribute__((ext_vector_type(8)));
typedef float f32x4 __attribute__((ext_vector_type(4)));

__device__ __forceinline__ unsigned short f16bits(_Float16 h) {
  union { _Float16 h; unsigned short u; } cv; cv.h = h; return cv.u;
}

// XOR swizzle on 16B chunks within a [row][64B] LDS tile row:
// chunk' = chunk ^ ((row>>1)&3). Involution; applied on write (or baked into
// the pre-swizzled global image) AND on read.
__device__ __forceinline__ int swz_chunk(int row, int chunk) {
  return chunk ^ ((row >> 1) & 3);
}

__device__ __forceinline__ void gload_lds16(const void* g, void* l) {
  __builtin_amdgcn_global_load_lds(
      (const __attribute__((address_space(1))) unsigned int*)g,
      (__attribute__((address_space(3))) unsigned int*)l, 16, 0, 0);
}

// ---------------------------------------------------------------------------
// Kernel 1: W1 [K=1536][N=512] fp32 -> pre-swizzled tiled fp16 hi/lo images.
// ws layout: [nblk 4][kt 48][hl 2][8192B tile]; tile image byte:
//   row*64 + swz_chunk(row, k>>3)*16 + (k&7)*2   (row = n within block)
// ---------------------------------------------------------------------------
__global__ __launch_bounds__(256) void convert_w1_kernel(
    const float* __restrict__ W1,
    unsigned short* __restrict__ W1ws)
{
  const int kt = blockIdx.x;       // 0..47
  const int nb = blockIdx.y;       // 0..3
  const int tid = threadIdx.x;
  const int k0 = kt * BKS, n0 = nb * BN;
  const size_t tbase = ((size_t)(nb * NKT + kt) * 2) * 4096;  // u16 units
#pragma unroll
  for (int i = 0; i < 16; ++i) {
    int idx = tid + i * 256;       // 0..4095
    int nn = idx & 127, kk = idx >> 7;
    float f = W1[(size_t)(k0 + kk) * NN + n0 + nn];
    _Float16 h = (_Float16)f;
    _Float16 l = (_Float16)((f - (float)h) * 2048.0f);
    int off16 = nn * 32 + (swz_chunk(nn, kk >> 3) << 3) + (kk & 7);
    W1ws[tbase + off16] = f16bits(h);
    W1ws[tbase + 4096 + off16] = f16bits(l);
  }
}

// ---------------------------------------------------------------------------
// Kernel 2: GEMM z = q @ W1 + b via fp16 split-3 MFMA, fused epilogue.
// B staged by global_load_lds from pre-swizzled images; A reg-converted with
// swizzled ds_write. FULL K per block (tanh needs complete z).
// partial -> raw_part[nb][row].
// ---------------------------------------------------------------------------
__global__ __launch_bounds__(256) void gemm_score_kernel(
    const float* __restrict__ query,
    const unsigned short* __restrict__ W1ws,
    const float* __restrict__ W1b,
    const float* __restrict__ Vw,
    float* __restrict__ raw_part)
{
  __shared__ _Float16 Ah[BM * 32];
  __shared__ _Float16 Al[BM * 32];
  __shared__ _Float16 Bh[BN * 32];
  __shared__ _Float16 Bl[BN * 32];
  __shared__ float red[2][BM];

  const int tid = threadIdx.x;
  const int lane = tid & 63;
  const int w = tid >> 6;
  const int wr = w >> 1, wc = w & 1;       // 2x2 waves, each 64x64
  const int lrow = lane & 15;
  const int lseg = lane >> 4;              // k-segment 0..3
  const int m0 = blockIdx.x * BM;
  const int nb = blockIdx.y;
  const int n0 = nb * BN;

  f32x4 zero = {0.f, 0.f, 0.f, 0.f};
  f32x4 acc[4][4];   // hh accumulation
  f32x4 acc2[4][4];  // (hl + lh) * 2^11 accumulation
#pragma unroll
  for (int m = 0; m < 4; ++m)
#pragma unroll
    for (int n = 0; n < 4; ++n) { acc[m][n] = zero; acc2[m][n] = zero; }

  const char* wbase = (const char*)W1ws;

  for (int kt = 0; kt < NKT; ++kt) {
    const int k0 = kt * BKS;
    __syncthreads();   // prev iteration's fragment reads complete

    // ---- B: async global->LDS, pre-swizzled image, 16B per lane ----
    {
      const size_t tb = ((size_t)(nb * NKT + kt) * 2) * 8192;
#pragma unroll
      for (int j = 0; j < 2; ++j) {
        int off = w * 2048 + j * 1024;
        gload_lds16(wbase + tb + off + lane * 16, (char*)Bh + off);
        gload_lds16(wbase + tb + 8192 + off + lane * 16, (char*)Bl + off);
      }
    }

    // ---- A: 128x32 fp32 -> hi/lo fp16 (lo scaled 2^11), swizzled ds_write --
#pragma unroll
    for (int i = 0; i < 4; ++i) {
      int q = tid + i * 256;               // 0..1023 float4 chunks
      int row = q >> 3, k4 = q & 7;
      const float4 v = *reinterpret_cast<const float4*>(
          &query[(size_t)(m0 + row) * KDIM + k0 + k4 * 4]);
      _Float16 h0 = (_Float16)v.x, h1 = (_Float16)v.y,
               h2 = (_Float16)v.z, h3 = (_Float16)v.w;
      _Float16 l0 = (_Float16)((v.x - (float)h0) * 2048.0f);
      _Float16 l1 = (_Float16)((v.y - (float)h1) * 2048.0f);
      _Float16 l2 = (_Float16)((v.z - (float)h2) * 2048.0f);
      _Float16 l3 = (_Float16)((v.w - (float)h3) * 2048.0f);
      uint2 hp, lp;
      hp.x = (unsigned)f16bits(h0) | ((unsigned)f16bits(h1) << 16);
      hp.y = (unsigned)f16bits(h2) | ((unsigned)f16bits(h3) << 16);
      lp.x = (unsigned)f16bits(l0) | ((unsigned)f16bits(l1) << 16);
      lp.y = (unsigned)f16bits(l2) | ((unsigned)f16bits(l3) << 16);
      int off = row * 64 + (swz_chunk(row, k4 >> 1) << 4) + ((k4 & 1) << 3);
      *reinterpret_cast<uint2*>((char*)Ah + off) = hp;
      *reinterpret_cast<uint2*>((char*)Al + off) = lp;
    }
    __syncthreads();   // drains vmcnt (B in LDS) + lgkm (A written)

    // ---- fragments (swizzled reads) + MFMA ----
    f16x8 afh[4], afl[4], bfh[4], bfl[4];
#pragma unroll
    for (int m = 0; m < 4; ++m) {
      int rowA = wr * 64 + m * 16 + lrow;
      int offA = rowA * 64 + (swz_chunk(rowA, lseg) << 4);
      afh[m] = *reinterpret_cast<const f16x8*>((const char*)Ah + offA);
      afl[m] = *reinterpret_cast<const f16x8*>((const char*)Al + offA);
    }
#pragma unroll
    for (int n = 0; n < 4; ++n) {
      int rowB = wc * 64 + n * 16 + lrow;
      int offB = rowB * 64 + (swz_chunk(rowB, lseg) << 4);
      bfh[n] = *reinterpret_cast<const f16x8*>((const char*)Bh + offB);
      bfl[n] = *reinterpret_cast<const f16x8*>((const char*)Bl + offB);
    }
#pragma unroll
    for (int m = 0; m < 4; ++m)
#pragma unroll
      for (int n = 0; n < 4; ++n) {
        acc[m][n]  = __builtin_amdgcn_mfma_f32_16x16x32_f16(afh[m], bfh[n], acc[m][n], 0, 0, 0);
        acc2[m][n] = __builtin_amdgcn_mfma_f32_16x16x32_f16(afh[m], bfl[n], acc2[m][n], 0, 0, 0);
        acc2[m][n] = __builtin_amdgcn_mfma_f32_16x16x32_f16(afl[m], bfh[n], acc2[m][n], 0, 0, 0);
      }
  }

  // ---- epilogue: z = acc + acc2*2^-11 + bias; tanh; dot with Vw ----
  float part[4][4];
#pragma unroll
  for (int m = 0; m < 4; ++m)
#pragma unroll
    for (int r = 0; r < 4; ++r) part[m][r] = 0.f;
#pragma unroll
  for (int n = 0; n < 4; ++n) {
    int col = n0 + wc * 64 + n * 16 + lrow;
    float bias = W1b[col];
    float vw = Vw[col];
#pragma unroll
    for (int m = 0; m < 4; ++m)
#pragma unroll
      for (int r = 0; r < 4; ++r) {
        float z = acc[m][n][r] + acc2[m][n][r] * 4.8828125e-4f + bias;
        part[m][r] += tanhf(z) * vw;
      }
  }
  // reduce across the 16 column-lanes (lane&15)
#pragma unroll
  for (int off = 1; off < 16; off <<= 1)
#pragma unroll
    for (int m = 0; m < 4; ++m)
#pragma unroll
      for (int r = 0; r < 4; ++r)
        part[m][r] += __shfl_xor(part[m][r], off, 64);
  if (lrow == 0) {
#pragma unroll
    for (int m = 0; m < 4; ++m)
#pragma unroll
      for (int r = 0; r < 4; ++r)
        red[wc][wr * 64 + m * 16 + (lane >> 4) * 4 + r] = part[m][r];
  }
  __syncthreads();
  if (tid < BM)
    raw_part[(size_t)nb * TM + m0 + tid] = red[0][tid] + red[1][tid];
}

// ---------------------------------------------------------------------------
// Kernel 3: per-cine (64 blocks x 1 wave): sum partials + Vb, stable rank,
// greedy temporal NMS (radius 13) with ballot keep-test, sigmoid -> probs
// ---------------------------------------------------------------------------
__global__ __launch_bounds__(64) void nms_kernel(
    const float* __restrict__ raw_part,
    const float* __restrict__ Vb,
    float* __restrict__ probs)
{
  const int cine = blockIdx.x;
  const int lane = threadIdx.x;
  __shared__ float s[256];
  __shared__ int order[256];
  float sv[4];
  const float vb = Vb[0];
#pragma unroll
  for (int q = 0; q < 4; ++q) {
    int p = q * 64 + lane;
    int idx = cine * 256 + p;
    float r = vb;
#pragma unroll
    for (int sl = 0; sl < 4; ++sl) r += raw_part[sl * TM + idx];
    sv[q] = r;
    s[p] = r;
  }
  __syncthreads();
  // stable rank (value desc, index asc)
#pragma unroll
  for (int q = 0; q < 4; ++q) {
    int p = q * 64 + lane;
    float st = sv[q];
    int rk = 0;
    for (int j = 0; j < 256; ++j) {
      float sj = s[j];
      rk += (sj > st) || (sj == st && j < p);
    }
    order[rk] = p;
  }
  __syncthreads();
  unsigned m = 0xFu;  // bit q alive for position q*64+lane
  for (int r = 0; r < 256; ++r) {
    int i = order[r];                 // uniform broadcast read
    int qi = i >> 6, li = i & 63;
    unsigned long long ball =
        __ballot((lane == li) && ((m >> qi) & 1u));
    if (ball) {
      // kept: clear window |p - i| <= 13, p != i
#pragma unroll
      for (int q = 0; q < 4; ++q) {
        int d = q * 64 + lane - i;
        if (d != 0 && d <= 13 && d >= -13) m &= ~(1u << q);
      }
    } else if (lane == li) {
      s[i] = -3.402823466385289e+38f;  // float32 min (NEG_INF)
    }
  }
  __syncthreads();
#pragma unroll
  for (int q = 0; q < 4; ++q) {
    int p = q * 64 + lane;
    probs[cine * 256 + p] = 1.0f / (1.0f + expf(-s[p]));
  }
}

// ---------------------------------------------------------------------------
// Kernel 4: per-batch (8 blocks) nucleus top-p(0.7) on 2048 probs.
// Writes attn (out+12288) and masked_score (out+28672).
// ---------------------------------------------------------------------------
__global__ __launch_bounds__(256) void topp_kernel(
    const float* __restrict__ probs,
    float* __restrict__ out)
{
  const int b = blockIdx.x;
  const int tid = threadIdx.x;
  __shared__ float p[2048];
  __shared__ int cnz[2048];
  __shared__ float sv[2048];
  __shared__ int sidx[2048];
  __shared__ unsigned char msk[2048];
  __shared__ float red[256];
  __shared__ int nnz_s;

  if (tid == 0) nnz_s = 0;
  for (int i = tid; i < 2048; i += 256) {
    p[i] = probs[b * 2048 + i];
    msk[i] = 0;
  }
  __syncthreads();
  float lsum = 0.f;
  for (int i = tid; i < 2048; i += 256) {
    float v = p[i];
    lsum += v;
    if (v > 0.f) {
      int slot = atomicAdd(&nnz_s, 1);
      cnz[slot] = i;
    }
  }
  red[tid] = lsum;
  __syncthreads();
  for (int sred = 128; sred > 0; sred >>= 1) {
    if (tid < sred) red[tid] += red[tid + sred];
    __syncthreads();
  }
  const int nnz = nnz_s;
  const float total = red[0];
  for (int c = tid; c < nnz; c += 256) {
    int i = cnz[c];
    float pi = p[i];
    int rank = 0;
    for (int cc = 0; cc < nnz; ++cc) {
      int j = cnz[cc];
      float pj = p[j];
      rank += (pj > pi) || (pj == pi && j < i);
    }
    sv[rank] = pi;
    sidx[rank] = i;
  }
  __syncthreads();
  if (tid == 0) {
    float denom = total + 1e-8f;
    float cum = 0.f;
    for (int r = 0; r < nnz; ++r) {
      cum += sv[r] / denom;             // norm then cumsum, like reference
      if ((cum <= 0.7f) || (r < 3)) msk[sidx[r]] = 1;
    }
  }
  __syncthreads();
  float ls = 0.f;
  for (int i = tid; i < 2048; i += 256) {
    float m = msk[i] ? p[i] : 0.f;
    sv[i] = m;
    ls += m;
  }
  red[tid] = ls;
  __syncthreads();
  for (int sred = 128; sred > 0; sred >>= 1) {
    if (tid < sred) red[tid] += red[tid + sred];
    __syncthreads();
  }
  const float ssum = red[0];
  const float denom = ssum + 1e-8f;
  const bool uni = (ssum <= 0.f);
  for (int i = tid; i < 2048; i += 256) {
    float m = sv[i];
    out[28672 + b * 2048 + i] = m;                       // masked_score
    out[12288 + b * 2048 + i] = uni ? (1.0f / 2048.0f) : (m / denom);  // attn
  }
}

// ---------------------------------------------------------------------------
// Kernel 5: fused sparse context: per (b, d-chunk) block, sum attn*values
// ---------------------------------------------------------------------------
__global__ __launch_bounds__(256) void ctx_kernel(
    const float* __restrict__ attn,     // out + 12288
    const float* __restrict__ values,
    float* __restrict__ out)
{
  const int b = blockIdx.x / 6;
  const int ch = blockIdx.x % 6;
  const int tid = threadIdx.x;
  const int d = ch * 256 + tid;
  __shared__ float a[2048];
  for (int i = tid; i < 2048; i += 256) a[i] = attn[b * 2048 + i];
  __syncthreads();
  float acc = 0.f;
  for (int ct = 0; ct < 2048; ++ct) {
    float at = a[ct];                    // block-uniform -> scalar branch
    if (at != 0.f)
      acc += at * values[((size_t)b * 2048 + ct) * KDIM + d];
  }
  out[b * KDIM + d] = acc;
}

// ---------------------------------------------------------------------------
extern "C" void kernel_launch(void* const* d_in, const int* in_sizes, int n_in,
                              void* d_out, int out_size, void* d_ws, size_t ws_size,
                              hipStream_t stream) {
  const float* query  = (const float*)d_in[0];
  const float* values = (const float*)d_in[1];
  const float* W1w    = (const float*)d_in[2];
  const float* W1b    = (const float*)d_in[3];
  const float* Vw     = (const float*)d_in[4];
  const float* Vb     = (const float*)d_in[5];
  float* out = (float*)d_out;

  // ws layout (bytes): W1ws tiles [4][48][2][8192] = 3145728 |
  //                    raw_part[4*16384 f32] | probs[16384 f32]
  unsigned short* W1ws = (unsigned short*)d_ws;
  float* raw_part = (float*)((char*)d_ws + 3145728);
  float* probs    = raw_part + 4 * TM;

  convert_w1_kernel<<<dim3(NKT, 4), 256, 0, stream>>>(W1w, W1ws);
  gemm_score_kernel<<<dim3(TM / BM, NN / BN), 256, 0, stream>>>(
      query, W1ws, W1b, Vw, raw_part);
  nms_kernel<<<64, 64, 0, stream>>>(raw_part, Vb, probs);
  topp_kernel<<<8, 256, 0, stream>>>(probs, out);
  ctx_kernel<<<48, 256, 0, stream>>>(out + 12288, values, out);
}

// Round 4
// 171.156 us; speedup vs baseline: 2.0373x; 2.0373x over previous
//
#include <hip/hip_runtime.h>
#include <math.h>
#include <stdint.h>

// Problem constants
#define TM 16384   // B*C*T rows
#define NN 512     // DOUT
#define KDIM 1536  // DIN
#define BM 128
#define BN 128
#define BKS 32
#define NKT 48     // total K-steps (full K per block: tanh needs complete z)

typedef _Float16 f16x8 __attribute__((ext_vector_type(8)));
typedef float f32x4 __attribute__((ext_vector_type(4)));

__device__ __forceinline__ unsigned short f16bits(_Float16 h) {
  union { _Float16 h; unsigned short u; } cv; cv.h = h; return cv.u;
}

// B-tile swizzle (fp16, 64B rows, 4x16B chunks): chunk' = chunk ^ ((row>>1)&3).
// Measured 0 bank conflicts in R3.
__device__ __forceinline__ int swz_chunk(int row, int chunk) {
  return chunk ^ ((row >> 1) & 3);
}

__device__ __forceinline__ void gload_lds16(const void* g, void* l) {
  __builtin_amdgcn_global_load_lds(
      (const __attribute__((address_space(1))) unsigned int*)g,
      (__attribute__((address_space(3))) unsigned int*)l, 16, 0, 0);
}

// ---------------------------------------------------------------------------
// Kernel 1: W1 [K=1536][N=512] fp32 -> pre-swizzled tiled fp16 hi/lo images.
// ws layout: [nblk 4][kt 48][hl 2][8192B tile]; tile image byte:
//   row*64 + swz_chunk(row, k>>3)*16 + (k&7)*2   (row = n within block)
// (unchanged from R3)
// ---------------------------------------------------------------------------
__global__ __launch_bounds__(256) void convert_w1_kernel(
    const float* __restrict__ W1,
    unsigned short* __restrict__ W1ws)
{
  const int kt = blockIdx.x;       // 0..47
  const int nb = blockIdx.y;       // 0..3
  const int tid = threadIdx.x;
  const int k0 = kt * BKS, n0 = nb * BN;
  const size_t tbase = ((size_t)(nb * NKT + kt) * 2) * 4096;  // u16 units
#pragma unroll
  for (int i = 0; i < 16; ++i) {
    int idx = tid + i * 256;       // 0..4095
    int nn = idx & 127, kk = idx >> 7;
    float f = W1[(size_t)(k0 + kk) * NN + n0 + nn];
    _Float16 h = (_Float16)f;
    _Float16 l = (_Float16)((f - (float)h) * 2048.0f);
    int off16 = nn * 32 + (swz_chunk(nn, kk >> 3) << 3) + (kk & 7);
    W1ws[tbase + off16] = f16bits(h);
    W1ws[tbase + 4096 + off16] = f16bits(l);
  }
}

// ---------------------------------------------------------------------------
// Kernel 2: GEMM z = q @ W1 + b via fp16 split-3 MFMA, fused tanh*Vw epilogue.
// T3-minimum 2-phase pipeline: dbuf LDS, all staging via global_load_lds,
// counted vmcnt(8), raw s_barrier. A staged as raw fp32 (source-swizzled),
// hi/lo split done in registers. FULL K per block.
// LDS buf layout (32KB): A f32 [128 rows][128B, chunk-swz row&7] | Bh 8KB | Bl 8KB
// ---------------------------------------------------------------------------
__global__ __launch_bounds__(256, 2) void gemm_score_kernel(
    const float* __restrict__ query,
    const unsigned short* __restrict__ W1ws,
    const float* __restrict__ W1b,
    const float* __restrict__ Vw,
    float* __restrict__ raw_part)
{
  __shared__ __align__(16) char ldsb[2][32768];
  __shared__ float red[2][BM];

  const int tid = threadIdx.x;
  const int lane = tid & 63;
  const int w = tid >> 6;
  const int wr = w >> 1, wc = w & 1;       // 2x2 waves, wave-tile 64x64
  const int lrow = lane & 15;
  const int lseg = lane >> 4;              // k-segment 0..3

  // XCD-chunked bijective swizzle (512 = 8 XCD * 64), n innermost per XCD
  const int bid = blockIdx.x;
  const int lin = (bid & 7) * 64 + (bid >> 3);
  const int mb = lin >> 2, nb = lin & 3;
  const int m0 = mb * BM, n0 = nb * BN;

  f32x4 zero = {0.f, 0.f, 0.f, 0.f};
  f32x4 acc[4][4];   // hh
  f32x4 acc2[4][4];  // (hl + lh) * 2^11
#pragma unroll
  for (int m = 0; m < 4; ++m)
#pragma unroll
    for (int n = 0; n < 4; ++n) { acc[m][n] = zero; acc2[m][n] = zero; }

  const char* wbase = (const char*)W1ws;

  // STAGE: issue 8 global_load_lds per thread for K-step kt into buf b.
  auto STAGE = [&](int kt, int bufi) {
    char* base = &ldsb[bufi][0];
    const int k0 = kt * BKS;
    // A: 16KB fp32, 4 wave-calls; source pre-swizzled so LDS-linear dest
    // yields layout byte = row*128 + (kc ^ (row&7))*16
#pragma unroll
    for (int j = 0; j < 4; ++j) {
      int chunk = (w * 4 + j) * 64 + lane;      // 16B chunk id 0..1023
      int row = chunk >> 3, cp = chunk & 7;
      int kc = cp ^ (row & 7);                  // logical k-chunk
      gload_lds16(query + (size_t)(m0 + row) * KDIM + k0 + kc * 4,
                  base + (w * 4 + j) * 1024);
    }
    // B: pre-swizzled images, linear
    const char* tb = wbase + ((size_t)(nb * NKT + kt) * 2) * 8192;
#pragma unroll
    for (int j = 0; j < 2; ++j) {
      int off = w * 2048 + j * 1024;
      gload_lds16(tb + off + lane * 16, base + 16384 + off);
      gload_lds16(tb + 8192 + off + lane * 16, base + 24576 + off);
    }
  };

  STAGE(0, 0);
  for (int kt = 0; kt < NKT; ++kt) {
    const int cur = kt & 1;
    if (kt + 1 < NKT) {
      STAGE(kt + 1, cur ^ 1);
      asm volatile("s_waitcnt vmcnt(8)" ::: "memory");  // cur's 8 landed
    } else {
      asm volatile("s_waitcnt vmcnt(0)" ::: "memory");
    }
    __builtin_amdgcn_s_barrier();            // all waves: cur tile ready

    const char* base = &ldsb[cur][0];
    // ---- A fragments: fp32 -> hi/lo fp16 in registers ----
    f16x8 afh[4], afl[4], bfh[4], bfl[4];
#pragma unroll
    for (int m = 0; m < 4; ++m) {
      int row = wr * 64 + m * 16 + lrow;
      int c0 = (lseg * 2) ^ (row & 7);
      int c1 = (lseg * 2 + 1) ^ (row & 7);
      f32x4 va = *reinterpret_cast<const f32x4*>(base + row * 128 + c0 * 16);
      f32x4 vb = *reinterpret_cast<const f32x4*>(base + row * 128 + c1 * 16);
      f16x8 h, l;
#pragma unroll
      for (int e = 0; e < 4; ++e) {
        _Float16 hh = (_Float16)va[e];
        h[e] = hh;
        l[e] = (_Float16)((va[e] - (float)hh) * 2048.0f);
      }
#pragma unroll
      for (int e = 0; e < 4; ++e) {
        _Float16 hh = (_Float16)vb[e];
        h[4 + e] = hh;
        l[4 + e] = (_Float16)((vb[e] - (float)hh) * 2048.0f);
      }
      afh[m] = h;
      afl[m] = l;
    }
    // ---- B fragments (swizzled reads) ----
#pragma unroll
    for (int n = 0; n < 4; ++n) {
      int row = wc * 64 + n * 16 + lrow;
      int off = row * 64 + (swz_chunk(row, lseg) << 4);
      bfh[n] = *reinterpret_cast<const f16x8*>(base + 16384 + off);
      bfl[n] = *reinterpret_cast<const f16x8*>(base + 24576 + off);
    }
    // ---- 48 MFMA ----
#pragma unroll
    for (int m = 0; m < 4; ++m)
#pragma unroll
      for (int n = 0; n < 4; ++n) {
        acc[m][n]  = __builtin_amdgcn_mfma_f32_16x16x32_f16(afh[m], bfh[n], acc[m][n], 0, 0, 0);
        acc2[m][n] = __builtin_amdgcn_mfma_f32_16x16x32_f16(afh[m], bfl[n], acc2[m][n], 0, 0, 0);
        acc2[m][n] = __builtin_amdgcn_mfma_f32_16x16x32_f16(afl[m], bfh[n], acc2[m][n], 0, 0, 0);
      }
    // ds_reads of cur complete before any wave overwrites it next iter
    asm volatile("s_waitcnt lgkmcnt(0)" ::: "memory");
    __builtin_amdgcn_s_barrier();
  }

  // ---- epilogue: z = acc + acc2*2^-11 + bias; tanh; dot with Vw ----
  float part[4][4];
#pragma unroll
  for (int m = 0; m < 4; ++m)
#pragma unroll
    for (int r = 0; r < 4; ++r) part[m][r] = 0.f;
#pragma unroll
  for (int n = 0; n < 4; ++n) {
    int col = n0 + wc * 64 + n * 16 + lrow;
    float bias = W1b[col];
    float vw = Vw[col];
#pragma unroll
    for (int m = 0; m < 4; ++m)
#pragma unroll
      for (int r = 0; r < 4; ++r) {
        float z = acc[m][n][r] + acc2[m][n][r] * 4.8828125e-4f + bias;
        part[m][r] += tanhf(z) * vw;
      }
  }
#pragma unroll
  for (int off = 1; off < 16; off <<= 1)
#pragma unroll
    for (int m = 0; m < 4; ++m)
#pragma unroll
      for (int r = 0; r < 4; ++r)
        part[m][r] += __shfl_xor(part[m][r], off, 64);
  if (lrow == 0) {
#pragma unroll
    for (int m = 0; m < 4; ++m)
#pragma unroll
      for (int r = 0; r < 4; ++r)
        red[wc][wr * 64 + m * 16 + (lane >> 4) * 4 + r] = part[m][r];
  }
  __syncthreads();
  if (tid < BM)
    raw_part[(size_t)nb * TM + m0 + tid] = red[0][tid] + red[1][tid];
}

// ---------------------------------------------------------------------------
// Kernel 3: per-cine (64 blocks x 1 wave): sum partials + Vb, stable rank,
// greedy temporal NMS (radius 13) with ballot keep-test, sigmoid -> probs
// ---------------------------------------------------------------------------
__global__ __launch_bounds__(64) void nms_kernel(
    const float* __restrict__ raw_part,
    const float* __restrict__ Vb,
    float* __restrict__ probs)
{
  const int cine = blockIdx.x;
  const int lane = threadIdx.x;
  __shared__ float s[256];
  __shared__ int order[256];
  float sv[4];
  const float vb = Vb[0];
#pragma unroll
  for (int q = 0; q < 4; ++q) {
    int p = q * 64 + lane;
    int idx = cine * 256 + p;
    float r = vb;
#pragma unroll
    for (int sl = 0; sl < 4; ++sl) r += raw_part[sl * TM + idx];
    sv[q] = r;
    s[p] = r;
  }
  __syncthreads();
#pragma unroll
  for (int q = 0; q < 4; ++q) {
    int p = q * 64 + lane;
    float st = sv[q];
    int rk = 0;
    for (int j = 0; j < 256; ++j) {
      float sj = s[j];
      rk += (sj > st) || (sj == st && j < p);
    }
    order[rk] = p;
  }
  __syncthreads();
  unsigned m = 0xFu;
  for (int r = 0; r < 256; ++r) {
    int i = order[r];
    int qi = i >> 6, li = i & 63;
    unsigned long long ball = __ballot((lane == li) && ((m >> qi) & 1u));
    if (ball) {
#pragma unroll
      for (int q = 0; q < 4; ++q) {
        int d = q * 64 + lane - i;
        if (d != 0 && d <= 13 && d >= -13) m &= ~(1u << q);
      }
    } else if (lane == li) {
      s[i] = -3.402823466385289e+38f;  // NEG_INF
    }
  }
  __syncthreads();
#pragma unroll
  for (int q = 0; q < 4; ++q) {
    int p = q * 64 + lane;
    probs[cine * 256 + p] = 1.0f / (1.0f + expf(-s[p]));
  }
}

// ---------------------------------------------------------------------------
// Kernel 4: per-batch (8 blocks) nucleus top-p(0.7) on 2048 probs.
// Writes attn (out+12288) and masked_score (out+28672).
// ---------------------------------------------------------------------------
__global__ __launch_bounds__(256) void topp_kernel(
    const float* __restrict__ probs,
    float* __restrict__ out)
{
  const int b = blockIdx.x;
  const int tid = threadIdx.x;
  __shared__ float p[2048];
  __shared__ int cnz[2048];
  __shared__ float sv[2048];
  __shared__ int sidx[2048];
  __shared__ unsigned char msk[2048];
  __shared__ float red[256];
  __shared__ int nnz_s;

  if (tid == 0) nnz_s = 0;
  for (int i = tid; i < 2048; i += 256) {
    p[i] = probs[b * 2048 + i];
    msk[i] = 0;
  }
  __syncthreads();
  float lsum = 0.f;
  for (int i = tid; i < 2048; i += 256) {
    float v = p[i];
    lsum += v;
    if (v > 0.f) {
      int slot = atomicAdd(&nnz_s, 1);
      cnz[slot] = i;
    }
  }
  red[tid] = lsum;
  __syncthreads();
  for (int sred = 128; sred > 0; sred >>= 1) {
    if (tid < sred) red[tid] += red[tid + sred];
    __syncthreads();
  }
  const int nnz = nnz_s;
  const float total = red[0];
  for (int c = tid; c < nnz; c += 256) {
    int i = cnz[c];
    float pi = p[i];
    int rank = 0;
    for (int cc = 0; cc < nnz; ++cc) {
      int j = cnz[cc];
      float pj = p[j];
      rank += (pj > pi) || (pj == pi && j < i);
    }
    sv[rank] = pi;
    sidx[rank] = i;
  }
  __syncthreads();
  if (tid == 0) {
    float denom = total + 1e-8f;
    float cum = 0.f;
    for (int r = 0; r < nnz; ++r) {
      cum += sv[r] / denom;
      if ((cum <= 0.7f) || (r < 3)) msk[sidx[r]] = 1;
    }
  }
  __syncthreads();
  float ls = 0.f;
  for (int i = tid; i < 2048; i += 256) {
    float m = msk[i] ? p[i] : 0.f;
    sv[i] = m;
    ls += m;
  }
  red[tid] = ls;
  __syncthreads();
  for (int sred = 128; sred > 0; sred >>= 1) {
    if (tid < sred) red[tid] += red[tid + sred];
    __syncthreads();
  }
  const float ssum = red[0];
  const float denom = ssum + 1e-8f;
  const bool uni = (ssum <= 0.f);
  for (int i = tid; i < 2048; i += 256) {
    float m = sv[i];
    out[28672 + b * 2048 + i] = m;                       // masked_score
    out[12288 + b * 2048 + i] = uni ? (1.0f / 2048.0f) : (m / denom);  // attn
  }
}

// ---------------------------------------------------------------------------
// Kernel 5: sparse context partials. grid = 8 b x 8 tgroup x 6 dchunk = 384.
// Ballot-compacted kept indices (deterministic order), ~19 rows per block.
// ---------------------------------------------------------------------------
__global__ __launch_bounds__(256) void ctx_part_kernel(
    const float* __restrict__ attn,     // out + 12288
    const float* __restrict__ values,
    float* __restrict__ ctxp)
{
  const int ch = blockIdx.x % 6;
  const int g  = (blockIdx.x / 6) & 7;
  const int b  = blockIdx.x / 48;
  const int tid = threadIdx.x;
  const int lane = tid & 63, w = tid >> 6;
  __shared__ float av[256];
  __shared__ int   idx[256];
  __shared__ int   wcnt[4];

  float a = attn[b * 2048 + g * 256 + tid];
  unsigned long long mask = __ballot(a != 0.f);
  if (lane == 0) wcnt[w] = __popcll(mask);
  __syncthreads();
  int base = 0;
  for (int i = 0; i < w; ++i) base += wcnt[i];
  if (a != 0.f) {
    int pos = base + __popcll(mask & ((1ull << lane) - 1ull));
    av[pos] = a;
    idx[pos] = g * 256 + tid;
  }
  __syncthreads();
  const int total = wcnt[0] + wcnt[1] + wcnt[2] + wcnt[3];
  const int d = ch * 256 + tid;
  float acc = 0.f;
#pragma unroll 4
  for (int t = 0; t < total; ++t)
    acc += av[t] * values[((size_t)b * 2048 + idx[t]) * KDIM + d];
  ctxp[((size_t)(b * 8 + g)) * KDIM + d] = acc;
}

__global__ __launch_bounds__(256) void ctx_reduce_kernel(
    const float* __restrict__ ctxp,
    float* __restrict__ out)
{
  const int i = blockIdx.x * 256 + threadIdx.x;  // 0..12287
  const int b = i / KDIM, d = i % KDIM;
  float sum = 0.f;
#pragma unroll
  for (int g = 0; g < 8; ++g) sum += ctxp[((size_t)(b * 8 + g)) * KDIM + d];
  out[i] = sum;
}

// ---------------------------------------------------------------------------
extern "C" void kernel_launch(void* const* d_in, const int* in_sizes, int n_in,
                              void* d_out, int out_size, void* d_ws, size_t ws_size,
                              hipStream_t stream) {
  const float* query  = (const float*)d_in[0];
  const float* values = (const float*)d_in[1];
  const float* W1w    = (const float*)d_in[2];
  const float* W1b    = (const float*)d_in[3];
  const float* Vw     = (const float*)d_in[4];
  const float* Vb     = (const float*)d_in[5];
  float* out = (float*)d_out;

  // ws layout (bytes): W1ws [4][48][2][8192] = 3145728 |
  //   raw_part[4*16384 f32] | probs[16384 f32] | ctxp[64*1536 f32]
  unsigned short* W1ws = (unsigned short*)d_ws;
  float* raw_part = (float*)((char*)d_ws + 3145728);
  float* probs    = raw_part + 4 * TM;
  float* ctxp     = probs + TM;

  convert_w1_kernel<<<dim3(NKT, 4), 256, 0, stream>>>(W1w, W1ws);
  gemm_score_kernel<<<512, 256, 0, stream>>>(query, W1ws, W1b, Vw, raw_part);
  nms_kernel<<<64, 64, 0, stream>>>(raw_part, Vb, probs);
  topp_kernel<<<8, 256, 0, stream>>>(probs, out);
  ctx_part_kernel<<<384, 256, 0, stream>>>(out + 12288, values, ctxp);
  ctx_reduce_kernel<<<48, 256, 0, stream>>>(ctxp, out);
}